// Round 1
// baseline (129.566 us; speedup 1.0000x reference)
//
#include <hip/hip_runtime.h>

// ConvPool: x(32,16,128,128) f32, weight(144,64), bias(64)
// -> VALID 3x3 conv (64 ch) + bias + relu + 2x2 maxpool -> out(32,64,63,63)
// Strategy: fp32 vector-FMA (no fp32 MFMA on CDNA4). Block = 1 batch x 8x8
// pooled tile; LDS holds 18x18x16 input patch + full weight [144][64].
// Thread = 1 pooled pixel x 16 output channels; wave = one o-group so weight
// reads are whole-wave broadcast float4 (conflict-free).

#define C_IN 16
#define H_IN 128
#define W_IN 128
#define OUTF 64
#define BATCH 32
#define HP 63
#define WP 63
#define TPH 8
#define TPW 8
#define IN_TH (TPH * 2 + 2) // 18
#define IN_TW (TPW * 2 + 2) // 18

__global__ __launch_bounds__(256, 2)
void convpool_kernel(const float* __restrict__ x,
                     const float* __restrict__ weight,
                     const float* __restrict__ bias,
                     float* __restrict__ out) {
  __shared__ __align__(16) float ws[144][64];            // 36 KB, [c*9+n*3+m][o]
  __shared__ __align__(16) float xs[C_IN][IN_TH][IN_TW]; // 20.25 KB

  const int tid = threadIdx.x;
  const int b = blockIdx.y;
  const int tile = blockIdx.x; // 0..63
  const int ty = tile >> 3, tx = tile & 7;
  const int row0 = ty * (TPH * 2); // input row base of tile
  const int col0 = tx * (TPW * 2);

  // ---- stage weights: 9216 floats = 2304 float4, straight copy ----
  {
    const float4* wsrc = (const float4*)weight;
    float4* wdst = (float4*)&ws[0][0];
#pragma unroll
    for (int i = 0; i < 9; ++i) wdst[tid + 256 * i] = wsrc[tid + 256 * i];
  }
  // ---- stage x tile: 16*18*18 = 5184 floats, clamp OOB to 0 ----
  for (int idx = tid; idx < C_IN * IN_TH * IN_TW; idx += 256) {
    int c = idx / (IN_TH * IN_TW);
    int rem = idx - c * (IN_TH * IN_TW);
    int r = rem / IN_TW;
    int col = rem - r * IN_TW;
    int gr = row0 + r, gc = col0 + col;
    float v = 0.0f;
    if (gr < H_IN && gc < W_IN) v = x[((b * C_IN + c) * H_IN + gr) * W_IN + gc];
    (&xs[0][0][0])[idx] = v;
  }
  __syncthreads();

  const int og = tid >> 6;  // wave id = o-group (0..3): o = og*16 + i
  const int lane = tid & 63;
  const int ph = lane >> 3, pw = lane & 7; // pooled pixel within tile

  float acc[16][4]; // [o-sub][conv position dy*2+dx]
#pragma unroll
  for (int i = 0; i < 16; ++i)
#pragma unroll
    for (int p = 0; p < 4; ++p) acc[i][p] = 0.0f;

  for (int c = 0; c < C_IN; ++c) {
    // 4x4 input window for this pooled pixel, this channel
    float xv[4][4];
#pragma unroll
    for (int r = 0; r < 4; ++r) {
      const float2* xp = (const float2*)&xs[c][2 * ph + r][2 * pw];
      float2 a = xp[0], bb = xp[1];
      xv[r][0] = a.x; xv[r][1] = a.y; xv[r][2] = bb.x; xv[r][3] = bb.y;
    }
#pragma unroll
    for (int j = 0; j < 9; ++j) {
      const int n = j / 3, m = j % 3;
      // 16 weights for (c, n, m), o = og*16..og*16+15: wave-uniform broadcast
      const float4* wp = (const float4*)&ws[c * 9 + j][og * 16];
      float4 w0 = wp[0], w1 = wp[1], w2 = wp[2], w3 = wp[3];
      float wreg[16] = {w0.x, w0.y, w0.z, w0.w, w1.x, w1.y, w1.z, w1.w,
                        w2.x, w2.y, w2.z, w2.w, w3.x, w3.y, w3.z, w3.w};
#pragma unroll
      for (int i = 0; i < 16; ++i) {
#pragma unroll
        for (int dy = 0; dy < 2; ++dy)
#pragma unroll
          for (int dx = 0; dx < 2; ++dx)
            acc[i][dy * 2 + dx] =
                fmaf(wreg[i], xv[dy + n][dx + m], acc[i][dy * 2 + dx]);
      }
    }
  }

  // ---- epilogue: maxpool (relu/max commute; bias uniform over window) ----
  const int gph = ty * TPH + ph, gpw = tx * TPW + pw;
  if (gph < HP && gpw < WP) {
#pragma unroll
    for (int i = 0; i < 16; ++i) {
      const int o = og * 16 + i;
      float mx = fmaxf(fmaxf(acc[i][0], acc[i][1]), fmaxf(acc[i][2], acc[i][3]));
      float v = mx + bias[o];
      v = v > 0.0f ? v : 0.0f;
      out[((b * OUTF + o) * HP + gph) * WP + gpw] = v;
    }
  }
}

extern "C" void kernel_launch(void* const* d_in, const int* in_sizes, int n_in,
                              void* d_out, int out_size, void* d_ws, size_t ws_size,
                              hipStream_t stream) {
  const float* x = (const float*)d_in[0];
  const float* w = (const float*)d_in[1];
  const float* bias = (const float*)d_in[2];
  float* out = (float*)d_out;
  dim3 grid(64, BATCH); // 8x8 pooled tiles x 32 batches
  convpool_kernel<<<grid, 256, 0, stream>>>(x, w, bias, out);
}

// Round 2
// 109.388 us; speedup vs baseline: 1.1845x; 1.1845x over previous
//
#include <hip/hip_runtime.h>

// ConvPool via bf16 split-MFMA (v_mfma_f32_32x32x16_bf16).
// x(32,16,128,128) f32, weight(144,64), bias(64) -> out(32,64,63,63) f32.
// Conv = sum over 9 taps of K=16 (channels) GEMM; A = im2col rows (spatial),
// B = weights. Precision: x and w split into bf16 hi+lo; compute
// Ah*Bh + Al*Bh + Ah*Bl (drop Al*Bl) -> ~2e-4 error, fp32-like.
// Block = (batch, pooled row): 4 input rows x 128 cols staged in LDS as
// [row][col][c16] bf16 (hi & lo), weights as [tap][o][c16] (hi & lo).
// 4 waves x 2 M-tiles (32 pos = 2 conv rows x 16 cols) x 2 N-frags (o 0-31,32-63).
// Pooling is fully in-lane given the 32x32 C layout; pooled tile staged in LDS
// (aliases xs) then written coalesced.

typedef __bf16 bf16x2 __attribute__((ext_vector_type(2)));
typedef __bf16 bf16x8 __attribute__((ext_vector_type(8)));
typedef float f32x16 __attribute__((ext_vector_type(16)));

#define MFMA32(A, B, C) __builtin_amdgcn_mfma_f32_32x32x16_bf16(A, B, C, 0, 0, 0)

__global__ __launch_bounds__(256, 2)
void convpool_mfma(const float* __restrict__ x,
                   const float* __restrict__ weight,
                   const float* __restrict__ bias,
                   float* __restrict__ out) {
  // xs: 4 rows x 132 cols (128 + 4 zero pad) x 16 c, elem offset (r*132+col)*16+c
  __shared__ __align__(16) __bf16 xsh[4 * 132 * 16];   // 16896 B
  __shared__ __align__(16) __bf16 xsl[4 * 132 * 16];   // 16896 B
  // bs: [tap9][o64][c16]
  __shared__ __align__(16) __bf16 bsh[9 * 64 * 16];    // 18432 B
  __shared__ __align__(16) __bf16 bsl[9 * 64 * 16];    // 18432 B  (total 70656 B)

  const int tid = threadIdx.x;
  const int pr = blockIdx.x;  // pooled row 0..62
  const int b = blockIdx.y;   // batch
  const int r0 = 2 * pr;      // input row base (rows r0..r0+3 all in range)

  // ---- stage x: hi/lo bf16, layout [r][col][c]; c-pairs packed as b32 ----
#pragma unroll
  for (int it = 0; it < 4; ++it) {
    int task = tid + 256 * it;      // 0..1023
    int g = task & 31;              // col group: cols 4g..4g+3
    int r = (task >> 5) & 3;        // row 0..3
    int q = task >> 7;              // channel pair 0..7 (c = 2q, 2q+1)
    const float4 v0 = *(const float4*)(x + ((b * 16 + 2 * q) * 128 + (r0 + r)) * 128 + 4 * g);
    const float4 v1 = *(const float4*)(x + ((b * 16 + 2 * q + 1) * 128 + (r0 + r)) * 128 + 4 * g);
    const float a0[4] = {v0.x, v0.y, v0.z, v0.w};
    const float a1[4] = {v1.x, v1.y, v1.z, v1.w};
#pragma unroll
    for (int j = 0; j < 4; ++j) {
      __bf16 h0 = (__bf16)a0[j];
      __bf16 h1 = (__bf16)a1[j];
      __bf16 l0 = (__bf16)(a0[j] - (float)h0);
      __bf16 l1 = (__bf16)(a1[j] - (float)h1);
      int eo = (r * 132 + 4 * g + j) * 16 + 2 * q;
      bf16x2 hv; hv[0] = h0; hv[1] = h1;
      bf16x2 lv; lv[0] = l0; lv[1] = l1;
      *(bf16x2*)(xsh + eo) = hv;
      *(bf16x2*)(xsl + eo) = lv;
    }
  }
  // zero-pad cols 128..131 (A-frags for the last M-tile read up to col 129)
  {
    int comp = tid >> 7, rem = tid & 127;
    int r = rem >> 5, col = 128 + ((rem >> 3) & 3), q = rem & 7;
    int eo = (r * 132 + col) * 16 + 2 * q;
    bf16x2 zv; zv[0] = (__bf16)0.0f; zv[1] = (__bf16)0.0f;
    *(bf16x2*)((comp ? xsl : xsh) + eo) = zv;
  }
  // ---- stage weights: [tap][o][c] hi/lo (k index in weight = c*9 + tap) ----
#pragma unroll
  for (int it = 0; it < 9; ++it) {
    int idx4 = tid + 256 * it;      // 0..2303
    int base = idx4 * 4;            // element index in weight (144*64)
    const float4 w4 = *(const float4*)(weight + base);
    int c = base / 576;             // 0..15
    int rem = base - c * 576;
    int tap = rem >> 6, o = rem & 63;  // o multiple of 4
    const float wv[4] = {w4.x, w4.y, w4.z, w4.w};
#pragma unroll
    for (int j = 0; j < 4; ++j) {
      __bf16 h = (__bf16)wv[j];
      __bf16 l = (__bf16)(wv[j] - (float)h);
      bsh[(tap * 64 + o + j) * 16 + c] = h;
      bsl[(tap * 64 + o + j) * 16 + c] = l;
    }
  }
  __syncthreads();

  const int lane = tid & 63;
  const int w = tid >> 6;        // wave id 0..3 -> conv cols [(2w)*16, (2w+2)*16)
  const int half = lane >> 5;    // k-group: channels half*8..half*8+7
  const int lo5 = lane & 31;     // B col / C col (o within frag)
  const int rr = (lane >> 4) & 1;  // A row: conv row offset within pair
  const int cc = lane & 15;        // A row: conv col within M-tile

  // B-hi fragments register-resident: 9 taps x 2 o-halves = 72 VGPR
  bf16x8 Bh[9][2];
#pragma unroll
  for (int t = 0; t < 9; ++t)
#pragma unroll
    for (int nf = 0; nf < 2; ++nf)
      Bh[t][nf] = *(const bf16x8*)(bsh + t * 1024 + (nf * 32 + lo5) * 16 + half * 8);

  f32x16 zero16;
#pragma unroll
  for (int i = 0; i < 16; ++i) zero16[i] = 0.0f;
  f32x16 acc[2][2];  // [m-tile][n-frag]
  acc[0][0] = zero16; acc[0][1] = zero16; acc[1][0] = zero16; acc[1][1] = zero16;

  const int xb0 = rr * 2112 + ((w * 2 + 0) * 16 + cc) * 16 + half * 8;
  const int xb1 = xb0 + 256;               // m-tile 1: +16 cols
  const int bb = lo5 * 16 + half * 8;      // B-frag offset within a tap (nf adds 512)

#pragma unroll
  for (int t = 0; t < 9; ++t) {
    const int n = t / 3, m = t - 3 * n;    // tap = n*3 + m (row, col offsets)
    const int xo = n * 2112 + m * 16;
    bf16x8 Ah0 = *(const bf16x8*)(xsh + xb0 + xo);
    bf16x8 Ah1 = *(const bf16x8*)(xsh + xb1 + xo);
    bf16x8 Al0 = *(const bf16x8*)(xsl + xb0 + xo);
    bf16x8 Al1 = *(const bf16x8*)(xsl + xb1 + xo);
    bf16x8 Bl0 = *(const bf16x8*)(bsl + t * 1024 + bb);
    bf16x8 Bl1 = *(const bf16x8*)(bsl + t * 1024 + 512 + bb);
    // 12 MFMA, 4 independent acc chains, dep distance 4
    acc[0][0] = MFMA32(Ah0, Bh[t][0], acc[0][0]);
    acc[1][0] = MFMA32(Ah1, Bh[t][0], acc[1][0]);
    acc[0][1] = MFMA32(Ah0, Bh[t][1], acc[0][1]);
    acc[1][1] = MFMA32(Ah1, Bh[t][1], acc[1][1]);
    acc[0][0] = MFMA32(Al0, Bh[t][0], acc[0][0]);
    acc[1][0] = MFMA32(Al1, Bh[t][0], acc[1][0]);
    acc[0][1] = MFMA32(Al0, Bh[t][1], acc[0][1]);
    acc[1][1] = MFMA32(Al1, Bh[t][1], acc[1][1]);
    acc[0][0] = MFMA32(Ah0, Bl0, acc[0][0]);
    acc[1][0] = MFMA32(Ah1, Bl0, acc[1][0]);
    acc[0][1] = MFMA32(Ah0, Bl1, acc[0][1]);
    acc[1][1] = MFMA32(Ah1, Bl1, acc[1][1]);
  }

  // ---- epilogue: in-lane 2x2 maxpool, stage pooled row in LDS, write out ----
  __syncthreads();                 // all waves done reading xs; ps aliases xsh
  float* ps = (float*)xsh;         // [o64][65] f32, 16640 B <= sizeof(xsh)
  const float bv0 = bias[lo5];
  const float bv1 = bias[32 + lo5];
#pragma unroll
  for (int mt = 0; mt < 2; ++mt) {
#pragma unroll
    for (int nf = 0; nf < 2; ++nf) {
      const f32x16 a = acc[mt][nf];
      const int o = nf * 32 + lo5;
      const float bvv = nf ? bv1 : bv0;
#pragma unroll
      for (int g = 0; g < 4; ++g) {
        // C rows: reg -> pos p = (reg&3) + 8*(reg>>2) + 4*half; 2x2 window =
        // regs {2g, 2g+1, 8+2g, 9+2g}
        float mx = fmaxf(fmaxf(a[2 * g], a[2 * g + 1]),
                         fmaxf(a[8 + 2 * g], a[9 + 2 * g]));
        float v = fmaxf(mx + bvv, 0.0f);
        int pcc = 2 * half + (g & 1) + 4 * (g >> 1);
        int pc = (w * 2 + mt) * 8 + pcc;   // pooled col 0..63 (63 unused)
        ps[o * 65 + pc] = v;
      }
    }
  }
  __syncthreads();
  {
    int o = tid >> 2, seg = tid & 3;
    int ob = ((b * 64 + o) * 63 + pr) * 63;
#pragma unroll
    for (int k = 0; k < 16; ++k) {
      int pc = seg * 16 + k;
      if (pc < 63) out[ob + pc] = ps[o * 65 + pc];
    }
  }
}

extern "C" void kernel_launch(void* const* d_in, const int* in_sizes, int n_in,
                              void* d_out, int out_size, void* d_ws, size_t ws_size,
                              hipStream_t stream) {
  const float* x = (const float*)d_in[0];
  const float* wgt = (const float*)d_in[1];
  const float* bias = (const float*)d_in[2];
  float* out = (float*)d_out;
  dim3 grid(63, 32);  // (pooled row, batch)
  convpool_mfma<<<grid, 256, 0, stream>>>(x, wgt, bias, out);
}

// Round 3
// 43.059 us; speedup vs baseline: 3.0090x; 2.5404x over previous
//
#include <hip/hip_runtime.h>

// ConvPool via bf16 split-MFMA (v_mfma_f32_32x32x16_bf16), round 3.
// x(32,16,128,128) f32, weight(144,64), bias(64) -> out(32,64,63,63) f32.
// Changes vs r2 (which was 82% LDS-bank-conflict stall, 5.46e7 conflict-cyc):
//  - staging writes are whole 16B granules at lane-consecutive LDS addresses
//    (addr = tid*16) -> conflict-free; main-loop b128 reads were already
//    bank-balanced (8 lanes per 4-bank group), so NO swizzle anywhere.
//  - weight hi/lo conversion hoisted to a one-off kernel into d_ws:
//    hi stored frag-ordered (direct per-lane register loads, L2-resident),
//    lo stored [t][o][c16] (linear 18KB LDS copy, conflict-free).
//  - LDS 70656 -> 51200 B.
// Precision: 3-term split AhBh + AlBh + AhBl (error ~2e-4, fp32-like).

typedef __bf16 bf16x8 __attribute__((ext_vector_type(8)));
typedef float f32x16 __attribute__((ext_vector_type(16)));

#define MFMA32(A, B, C) __builtin_amdgcn_mfma_f32_32x32x16_bf16(A, B, C, 0, 0, 0)

// ws layout (bytes): [0,18432) B_hi frag-ordered: (t*2+nf)*1024 + lane*16,
//   lane = cgrp*32 + (o&31), elem j -> hi(weight[((cgrp*8+j)*9+t)*64 + o])
// [18432,36864) B_lo: (t*64+o)*32 + cgrp*16 + j*2
__global__ void convert_b(const float* __restrict__ weight, char* __restrict__ ws) {
  int tau = blockIdx.x * 256 + threadIdx.x;
  if (tau >= 1152) return;            // 9 taps x 64 o x 2 c-groups
  int t = tau >> 7;                   // 0..8
  int r = tau & 127;
  int o = r >> 1, hf = r & 1;         // o 0..63, c-group 0..1
  __bf16 hi[8], lo[8];
#pragma unroll
  for (int j = 0; j < 8; ++j) {
    float v = weight[((hf * 8 + j) * 9 + t) * 64 + o];
    __bf16 h = (__bf16)v;
    hi[j] = h;
    lo[j] = (__bf16)(v - (float)h);
  }
  int nf = o >> 5, lo5 = o & 31;
  *(bf16x8*)(ws + (t * 2 + nf) * 1024 + (hf * 32 + lo5) * 16) = *(bf16x8*)hi;
  *(bf16x8*)(ws + 18432 + (t * 64 + o) * 32 + hf * 16) = *(bf16x8*)lo;
}

// LDS map (bytes): [0,16384) xs_hi [row4][col128][c16] bf16
//                  [16384,32768) xs_lo (same layout)
//                  [32768,51200) B_lo [t9][o64][c16] bf16
// epilogue ps[64][65] f32 aliases [0,16640)
__global__ __launch_bounds__(256, 2)
void convpool_main(const float* __restrict__ x, const char* __restrict__ ws,
                   const float* __restrict__ bias, float* __restrict__ out) {
  __shared__ __align__(16) char lds[51200];
  const int tid = threadIdx.x;
  const int pr = blockIdx.x;  // pooled row 0..62
  const int b = blockIdx.y;   // batch
  const int r0 = 2 * pr;      // input row base (rows r0..r0+3, all <= 127)
  const int lane = tid & 63;
  const int wv = tid >> 6;        // wave -> conv cols [wv*32, wv*32+32)
  const int half = lane >> 5;     // k-group: channels half*8..+8
  const int lo5 = lane & 31;      // B/C col (o)
  const int rr = (lane >> 4) & 1; // A row: conv row within pair
  const int cc = lane & 15;       // A row: conv col within m-tile

  // ---- B_hi fragments -> registers (36 x 16B, L2-resident broadcast) ----
  bf16x8 Bh[9][2];
#pragma unroll
  for (int t = 0; t < 9; ++t)
#pragma unroll
    for (int nf = 0; nf < 2; ++nf)
      Bh[t][nf] = *(const bf16x8*)(ws + (t * 2 + nf) * 1024 + lane * 16);

  // ---- B_lo -> LDS: linear 18432B copy, lane-consecutive 16B granules ----
#pragma unroll
  for (int k = 0; k < 5; ++k) {
    int idx = tid + 256 * k;
    if (idx < 1152)
      *(float4*)(lds + 32768 + idx * 16) =
          *(const float4*)(ws + 18432 + idx * 16);
  }

  // ---- x staging: thread owns (col=tid>>1, cgrp=tid&1), rows 0..3 ----
  // LDS write addr = row*4096 + tid*16 -> wave-contiguous, conflict-free.
  {
    const int col = tid >> 1, hf = tid & 1;
#pragma unroll
    for (int row = 0; row < 4; ++row) {
      float v[8];
#pragma unroll
      for (int j = 0; j < 8; ++j)
        v[j] = x[((b * 16 + hf * 8 + j) * 128 + (r0 + row)) * 128 + col];
      __bf16 hi[8], lo[8];
#pragma unroll
      for (int j = 0; j < 8; ++j) {
        __bf16 h = (__bf16)v[j];
        hi[j] = h;
        lo[j] = (__bf16)(v[j] - (float)h);
      }
      const int a = row * 4096 + col * 32 + hf * 16;
      *(bf16x8*)(lds + a) = *(bf16x8*)hi;
      *(bf16x8*)(lds + 16384 + a) = *(bf16x8*)lo;
    }
  }
  __syncthreads();

  f32x16 acc[2][2];
#pragma unroll
  for (int i = 0; i < 16; ++i) {
    acc[0][0][i] = 0.f; acc[0][1][i] = 0.f;
    acc[1][0][i] = 0.f; acc[1][1][i] = 0.f;
  }

  const int colb = wv * 32 + cc;
#pragma unroll
  for (int t = 0; t < 9; ++t) {
    const int n = t / 3, m = t - 3 * n;
    // A reads: cols up to colb+16+m <= 129 run past the row -> garbage that
    // only feeds conv cols 126/127 (pooled col 63, discarded); stays in-bounds.
    const int a0 = (rr + n) * 4096 + (colb + m) * 32 + half * 16;
    const int a1 = a0 + 512;  // m-tile 1: +16 cols
    bf16x8 Ah0 = *(const bf16x8*)(lds + a0);
    bf16x8 Ah1 = *(const bf16x8*)(lds + a1);
    bf16x8 Al0 = *(const bf16x8*)(lds + 16384 + a0);
    bf16x8 Al1 = *(const bf16x8*)(lds + 16384 + a1);
    const int ab = 32768 + t * 2048 + lo5 * 32 + half * 16;
    bf16x8 Bl0 = *(const bf16x8*)(lds + ab);
    bf16x8 Bl1 = *(const bf16x8*)(lds + ab + 1024);
    // 12 MFMA, 4 independent acc chains
    acc[0][0] = MFMA32(Ah0, Bh[t][0], acc[0][0]);
    acc[1][0] = MFMA32(Ah1, Bh[t][0], acc[1][0]);
    acc[0][1] = MFMA32(Ah0, Bh[t][1], acc[0][1]);
    acc[1][1] = MFMA32(Ah1, Bh[t][1], acc[1][1]);
    acc[0][0] = MFMA32(Al0, Bh[t][0], acc[0][0]);
    acc[1][0] = MFMA32(Al1, Bh[t][0], acc[1][0]);
    acc[0][1] = MFMA32(Al0, Bh[t][1], acc[0][1]);
    acc[1][1] = MFMA32(Al1, Bh[t][1], acc[1][1]);
    acc[0][0] = MFMA32(Ah0, Bl0, acc[0][0]);
    acc[1][0] = MFMA32(Ah1, Bl0, acc[1][0]);
    acc[0][1] = MFMA32(Ah0, Bl1, acc[0][1]);
    acc[1][1] = MFMA32(Ah1, Bl1, acc[1][1]);
  }

  // ---- epilogue: in-lane 2x2 maxpool (verified r2 mapping), stage, write ----
  __syncthreads();
  float* ps = (float*)lds;  // [o64][65] f32, 16640 B
  const float bv0 = bias[lo5];
  const float bv1 = bias[32 + lo5];
#pragma unroll
  for (int mt = 0; mt < 2; ++mt) {
#pragma unroll
    for (int nf = 0; nf < 2; ++nf) {
      const f32x16 a = acc[mt][nf];
      const int o = nf * 32 + lo5;
      const float bvv = nf ? bv1 : bv0;
#pragma unroll
      for (int g = 0; g < 4; ++g) {
        float mx = fmaxf(fmaxf(a[2 * g], a[2 * g + 1]),
                         fmaxf(a[8 + 2 * g], a[9 + 2 * g]));
        float v = fmaxf(mx + bvv, 0.0f);
        int pcc = 2 * half + (g & 1) + 4 * (g >> 1);
        int pc = (wv * 2 + mt) * 8 + pcc;  // 0..63 (63 discarded)
        ps[o * 65 + pc] = v;
      }
    }
  }
  __syncthreads();
  {
    int o = tid >> 2, seg = tid & 3;
    int ob = ((b * 64 + o) * 63 + pr) * 63;
#pragma unroll
    for (int k2 = 0; k2 < 16; ++k2) {
      int pc = seg * 16 + k2;
      if (pc < 63) out[ob + pc] = ps[o * 65 + pc];
    }
  }
}

extern "C" void kernel_launch(void* const* d_in, const int* in_sizes, int n_in,
                              void* d_out, int out_size, void* d_ws, size_t ws_size,
                              hipStream_t stream) {
  const float* x = (const float*)d_in[0];
  const float* wgt = (const float*)d_in[1];
  const float* bias = (const float*)d_in[2];
  float* out = (float*)d_out;
  char* ws = (char*)d_ws;  // needs 36864 B
  convert_b<<<dim3(5), 256, 0, stream>>>(wgt, ws);
  convpool_main<<<dim3(63, 32), 256, 0, stream>>>(x, ws, bias, out);
}

// Round 4
// 37.993 us; speedup vs baseline: 3.4103x; 1.1334x over previous
//
#include <hip/hip_runtime.h>

// ConvPool r4: streaming row pipeline, bf16 split-MFMA (32x32x16).
// x(32,16,128,128) f32, weight(144,64), bias(64) -> out(32,64,63,63) f32.
// Block = (batch, strip of 4 pooled rows), grid 16x32 = 512 = 2 blocks/CU.
// Per step: compute pooled row pr from 4-slot LDS x-ring; barrier;
// {store pooled row, load+convert+ds_write next 2 input rows}; barrier.
// B (weights) hi+lo fragments fully register-resident (144 VGPR), so the
// MFMA loop reads only A from LDS (36 ds_read_b128 : 108 MFMA per row/wave).
// LDS layout is 16-lane-contiguous everywhere -> no bank conflicts.
// Precision: 3-term split AhBh + AlBh + AhBl (as r2/r3, verified).

typedef __bf16 bf16x8 __attribute__((ext_vector_type(8)));
typedef float f32x16 __attribute__((ext_vector_type(16)));

#define MFMA32(A, B, C) __builtin_amdgcn_mfma_f32_32x32x16_bf16(A, B, C, 0, 0, 0)

// ws: [0,18432) B_hi frags, [18432,36864) B_lo frags.
// frag addr: (t*2+nf)*1024 + (hf*32+lo5)*16 + j*2
//   value = cvt(weight[((hf*8+j)*9 + t)*64 + nf*32+lo5])
__global__ void convert_b(const float* __restrict__ weight, char* __restrict__ ws) {
  int tau = blockIdx.x * 256 + threadIdx.x;
  if (tau >= 1152) return;          // 9 taps x 64 o x 2 ch-groups
  int t = tau >> 7;
  int r = tau & 127;
  int o = r >> 1, hf = r & 1;
  __bf16 hi[8], lo[8];
#pragma unroll
  for (int j = 0; j < 8; ++j) {
    float v = weight[((hf * 8 + j) * 9 + t) * 64 + o];
    __bf16 h = (__bf16)v;
    hi[j] = h;
    lo[j] = (__bf16)(v - (float)h);
  }
  int nf = o >> 5, lo5 = o & 31;
  int off = (t * 2 + nf) * 1024 + (hf * 32 + lo5) * 16;
  *(bf16x8*)(ws + off) = *(bf16x8*)hi;
  *(bf16x8*)(ws + 18432 + off) = *(bf16x8*)lo;
}

// Load one input row -> convert -> ds_write into its ring slot.
__device__ __forceinline__ void stage_row(char* lds, const float* xb, int r,
                                          int colS, int hfS) {
  float v[8];
#pragma unroll
  for (int j = 0; j < 8; ++j) v[j] = xb[j * 16384 + r * 128];
  __bf16 hi[8], lo[8];
#pragma unroll
  for (int j = 0; j < 8; ++j) {
    __bf16 h = (__bf16)v[j];
    hi[j] = h;
    lo[j] = (__bf16)(v[j] - (float)h);
  }
  int a = ((r & 3) << 13) + hfS * 2048 + colS * 16;
  *(bf16x8*)(lds + a) = *(bf16x8*)hi;          // hl=0 (hi)
  *(bf16x8*)(lds + a + 4096) = *(bf16x8*)lo;   // hl=1 (lo)
}

// LDS: [0,32768) x ring: slot(row&3)*8192 + hl*4096 + half*2048 + col*16
//      [32768,48896) ps[64][63] f32
__global__ __launch_bounds__(256, 2)
void convpool_main(const float* __restrict__ x, const char* __restrict__ ws,
                   const float* __restrict__ bias, float* __restrict__ out) {
  __shared__ __align__(16) char lds[48896];
  const int tid = threadIdx.x;
  const int s = blockIdx.x;            // strip 0..15
  const int b = blockIdx.y;            // batch
  const int nr = min(4, 63 - 4 * s);   // 4 rows (3 for strip 15)
  const int rb = 8 * s;                // input row base
  const int lane = tid & 63;
  const int wv = tid >> 6;
  const int half = lane >> 5;
  const int lo5 = lane & 31;
  const int rr = (lane >> 4) & 1;
  const int cc = lane & 15;
  const int colS = tid >> 1;           // staging col
  const int hfS = tid & 1;             // staging ch-group
  const float* xb = x + (b * 16 + hfS * 8) * 16384 + colS;

  // ---- B hi+lo fragments -> registers (36+36 b128 loads, L2-resident) ----
  bf16x8 Bh[9][2], Bl[9][2];
#pragma unroll
  for (int t = 0; t < 9; ++t)
#pragma unroll
    for (int nf = 0; nf < 2; ++nf) {
      int off = (t * 2 + nf) * 1024 + lane * 16;
      Bh[t][nf] = *(const bf16x8*)(ws + off);
      Bl[t][nf] = *(const bf16x8*)(ws + 18432 + off);
    }

  // ---- prologue: stage rows rb..rb+3 into slots 0..3 ----
#pragma unroll
  for (int r = 0; r < 4; ++r) stage_row(lds, xb, rb + r, colS, hfS);
  __syncthreads();

  float* ps = (float*)(lds + 32768);
  const float bv0 = bias[lo5];
  const float bv1 = bias[32 + lo5];
  const int colb16 = half * 2048 + (wv * 32 + cc) * 16;

  for (int i = 0; i < nr; ++i) {
    const int pr = 4 * s + i;
    const int i2 = 2 * i;

    f32x16 acc[2][2];
#pragma unroll
    for (int q = 0; q < 16; ++q) {
      acc[0][0][q] = 0.f; acc[0][1][q] = 0.f;
      acc[1][0][q] = 0.f; acc[1][1][q] = 0.f;
    }

#pragma unroll
    for (int t = 0; t < 9; ++t) {
      const int n = t / 3, m = t - 3 * n;
      // slot of input row 2*pr + rr + n  (rb multiple of 8 -> drop rb)
      const int sb = ((i2 + rr + n) & 3) << 13;
      const int a0 = sb + colb16 + m * 16;
      const int a1 = a0 + 256;  // m-tile 1: +16 cols
      // cols up to 129 bleed into lo-plane/ps: garbage feeding only pooled
      // col 63, which is discarded; stays within the lds allocation.
      bf16x8 Ah0 = *(const bf16x8*)(lds + a0);
      bf16x8 Ah1 = *(const bf16x8*)(lds + a1);
      bf16x8 Al0 = *(const bf16x8*)(lds + a0 + 4096);
      bf16x8 Al1 = *(const bf16x8*)(lds + a1 + 4096);
      acc[0][0] = MFMA32(Ah0, Bh[t][0], acc[0][0]);
      acc[1][0] = MFMA32(Ah1, Bh[t][0], acc[1][0]);
      acc[0][1] = MFMA32(Ah0, Bh[t][1], acc[0][1]);
      acc[1][1] = MFMA32(Ah1, Bh[t][1], acc[1][1]);
      acc[0][0] = MFMA32(Al0, Bh[t][0], acc[0][0]);
      acc[1][0] = MFMA32(Al1, Bh[t][0], acc[1][0]);
      acc[0][1] = MFMA32(Al0, Bh[t][1], acc[0][1]);
      acc[1][1] = MFMA32(Al1, Bh[t][1], acc[1][1]);
      acc[0][0] = MFMA32(Ah0, Bl[t][0], acc[0][0]);
      acc[1][0] = MFMA32(Ah1, Bl[t][0], acc[1][0]);
      acc[0][1] = MFMA32(Ah0, Bl[t][1], acc[0][1]);
      acc[1][1] = MFMA32(Ah1, Bl[t][1], acc[1][1]);
    }

    // ---- in-lane 2x2 maxpool -> ps[o][63] (r3-verified mapping) ----
#pragma unroll
    for (int mt = 0; mt < 2; ++mt)
#pragma unroll
      for (int nf = 0; nf < 2; ++nf) {
        const f32x16 a = acc[mt][nf];
        const int o = nf * 32 + lo5;
        const float bvv = nf ? bv1 : bv0;
#pragma unroll
        for (int g = 0; g < 4; ++g) {
          float mx = fmaxf(fmaxf(a[2 * g], a[2 * g + 1]),
                           fmaxf(a[8 + 2 * g], a[9 + 2 * g]));
          float v = fmaxf(mx + bvv, 0.0f);
          int pcc = 2 * half + (g & 1) + 4 * (g >> 1);
          int pc = (wv * 2 + mt) * 8 + pcc;
          if (pc < 63) ps[o * 63 + pc] = v;
        }
      }
    __syncthreads();

    // ---- phase B: stage next 2 input rows; store pooled row ----
    if (i < nr - 1) {
      stage_row(lds, xb, rb + i2 + 4, colS, hfS);
      stage_row(lds, xb, rb + i2 + 5, colS, hfS);
    }
    {
      const int ob = ((b * 64) * 63 + pr) * 63;  // + o*63*63 + pc
#pragma unroll
      for (int v = 0; v < 16; ++v) {
        int idx = tid + 256 * v;
        if (idx < 4032) {
          int o = idx / 63;
          int pc = idx - o * 63;
          out[ob + o * 3969 + pc] = ps[idx];
        }
      }
    }
    __syncthreads();
  }
}

extern "C" void kernel_launch(void* const* d_in, const int* in_sizes, int n_in,
                              void* d_out, int out_size, void* d_ws, size_t ws_size,
                              hipStream_t stream) {
  const float* x = (const float*)d_in[0];
  const float* wgt = (const float*)d_in[1];
  const float* bias = (const float*)d_in[2];
  float* out = (float*)d_out;
  char* ws = (char*)d_ws;  // needs 36864 B
  convert_b<<<dim3(5), 256, 0, stream>>>(wgt, ws);
  convpool_main<<<dim3(16, 32), 256, 0, stream>>>(x, ws, bias, out);
}